// Round 2
// baseline (36833.401 us; speedup 1.0000x reference)
//
#include <hip/hip_runtime.h>
#include <hip/hip_bf16.h>
#include <math.h>

#define T_ 512
#define B_ 64
#define E_ 256
#define H_ 600
#define G4 2400    // 4*H
#define MTOT 32768 // T*B

// ---------------- generic zero
__global__ __launch_bounds__(256) void zero_kernel(float* __restrict__ p, int n) {
    int i = blockIdx.x * 256 + threadIdx.x;
    if (i < n) p[i] = 0.f;
}

// ---------------- embedding gather: xT[k][m] = embed[us[b,t]*E + k], m = t*64+b
__global__ __launch_bounds__(256) void gather_xT(const int* __restrict__ us,
                                                 const float* __restrict__ embed,
                                                 float* __restrict__ xT) {
    int lane = threadIdx.x & 63;
    int m = blockIdx.x * 64 + lane;
    int b = m & 63, t = m >> 6;
    int tok = us[b * T_ + t];
    for (int k = threadIdx.x >> 6; k < E_; k += 4)
        xT[(size_t)k * MTOT + m] = embed[(size_t)tok * E_ + k];
}

// ---------------- Wc = W1 @ W2  [1200,4], bc = bm1 @ W2 + bm2  [4]
__global__ void wc_kernel(const float* __restrict__ W1, const float* __restrict__ bm1,
                          const float* __restrict__ W2, const float* __restrict__ bm2,
                          float* __restrict__ Wc, float* __restrict__ bc) {
    int idx = blockIdx.x * 256 + threadIdx.x;
    if (idx < 4800) {
        int k = idx >> 2, l = idx & 3;
        float acc = 0.f;
        for (int j = 0; j < 600; ++j) acc += W1[(size_t)k * 600 + j] * W2[j * 4 + l];
        Wc[idx] = acc;
    }
    if (idx < 4) {
        float acc = bm2[idx];
        for (int j = 0; j < 600; ++j) acc += bm1[j] * W2[j * 4 + idx];
        bc[idx] = acc;
    }
}

// ---------------- fp32 GEMM:  CT[n][m_local] = sum_k AT[k][m_off+m_local] * W[n][k]
#define GBM 128
#define GBN 128
#define GBK 16
__global__ __launch_bounds__(256) void gemm_nt(const float* __restrict__ AT, int lda, int m_off,
                                               const float* __restrict__ W, int N, int K,
                                               float* __restrict__ CT, int ldc) {
    __shared__ float As[GBK][GBM + 4];
    __shared__ float Ws[GBK][GBN + 4];
    int tid = threadIdx.x;
    int n0 = blockIdx.x * GBN;
    int m0 = blockIdx.y * GBM;
    int tx = tid & 15, ty = tid >> 4;
    float acc[8][8] = {};
    for (int k0 = 0; k0 < K; k0 += GBK) {
        {
            int kk = tid >> 4;
            int mm = (tid & 15) * 8;
            const float* src = AT + (size_t)(k0 + kk) * lda + m_off + m0 + mm;
            float4 v0 = ((const float4*)src)[0];
            float4 v1 = ((const float4*)src)[1];
            *(float4*)&As[kk][mm] = v0;
            *(float4*)&As[kk][mm + 4] = v1;
        }
        {
            int nn = tid >> 1;
            int kh = (tid & 1) * 8;
            int n = n0 + nn;
            float4 v0 = make_float4(0.f, 0.f, 0.f, 0.f), v1 = v0;
            if (n < N) {
                const float* src = W + (size_t)n * K + k0 + kh;
                v0 = ((const float4*)src)[0];
                v1 = ((const float4*)src)[1];
            }
            Ws[kh + 0][nn] = v0.x; Ws[kh + 1][nn] = v0.y; Ws[kh + 2][nn] = v0.z; Ws[kh + 3][nn] = v0.w;
            Ws[kh + 4][nn] = v1.x; Ws[kh + 5][nn] = v1.y; Ws[kh + 6][nn] = v1.z; Ws[kh + 7][nn] = v1.w;
        }
        __syncthreads();
#pragma unroll
        for (int kk = 0; kk < GBK; ++kk) {
            float a[8], w[8];
            *(float4*)&a[0] = *(float4*)&As[kk][tx * 8];
            *(float4*)&a[4] = *(float4*)&As[kk][tx * 8 + 4];
            *(float4*)&w[0] = *(float4*)&Ws[kk][ty * 8];
            *(float4*)&w[4] = *(float4*)&Ws[kk][ty * 8 + 4];
#pragma unroll
            for (int j = 0; j < 8; ++j)
#pragma unroll
                for (int i = 0; i < 8; ++i)
                    acc[j][i] = fmaf(w[j], a[i], acc[j][i]);
        }
        __syncthreads();
    }
    for (int j = 0; j < 8; ++j) {
        int n = n0 + ty * 8 + j;
        if (n < N) {
            float* dst = CT + (size_t)n * ldc + m0 + tx * 8;
            *(float4*)dst = *(float4*)&acc[j][0];
            *(float4*)(dst + 4) = *(float4*)&acc[j][4];
        }
    }
}

// ---------------- one LSTM time step, both directions.
// grid: 300 blocks (150/dir, 4 hidden units per block, 1 per wave), 256 threads
__global__ __launch_bounds__(256) void lstm_step(
    const float* __restrict__ preF, const float* __restrict__ preB, int pre_ld,
    int sF, int sB,
    const float* __restrict__ WhhF, const float* __restrict__ WhhB,
    const float* __restrict__ biasF, const float* __restrict__ biasB,
    const float* __restrict__ hInF, float* __restrict__ hOutF, float* __restrict__ cF,
    const float* __restrict__ hInB, float* __restrict__ hOutB, float* __restrict__ cB,
    float* __restrict__ outF, int colF, float* __restrict__ outB, int colB, int out_ld) {
    __shared__ float lh[60 * 64];
    int tid = threadIdx.x;
    int lane = tid & 63;
    int dir = (blockIdx.x >= 150) ? 1 : 0;
    int jb = blockIdx.x - dir * 150;
    int j = __builtin_amdgcn_readfirstlane(jb * 4 + (tid >> 6));
    const float* pre = dir ? preB : preF;
    const float* Whh = dir ? WhhB : WhhF;
    const float* bias = dir ? biasB : biasF;
    const float* hIn = dir ? hInB : hInF;
    float* hOut = dir ? hOutB : hOutF;
    float* cSt = dir ? cB : cF;
    float* outD = dir ? outB : outF;
    int s = dir ? sB : sF;
    int col = dir ? colB : colF;

    const float* w0 = Whh + (size_t)(0 * H_ + j) * H_;
    const float* w1 = Whh + (size_t)(1 * H_ + j) * H_;
    const float* w2 = Whh + (size_t)(2 * H_ + j) * H_;
    const float* w3 = Whh + (size_t)(3 * H_ + j) * H_;

    float a0 = 0.f, a1 = 0.f, a2 = 0.f, a3 = 0.f;
    for (int k0 = 0; k0 < H_; k0 += 60) {
        __syncthreads();
        {
            const float4* src = (const float4*)(hIn + (size_t)k0 * 64);
            float4* dst = (float4*)lh;
            for (int u = tid; u < 960; u += 256) dst[u] = src[u];
        }
        __syncthreads();
#pragma unroll
        for (int kk = 0; kk < 60; ++kk) {
            float hv = lh[kk * 64 + lane];
            a0 = fmaf(hv, w0[k0 + kk], a0);
            a1 = fmaf(hv, w1[k0 + kk], a1);
            a2 = fmaf(hv, w2[k0 + kk], a2);
            a3 = fmaf(hv, w3[k0 + kk], a3);
        }
    }
    int r = s * 64 + lane;
    float gi = pre[(size_t)(0 * H_ + j) * pre_ld + r] + bias[0 * H_ + j] + a0;
    float gf = pre[(size_t)(1 * H_ + j) * pre_ld + r] + bias[1 * H_ + j] + a1;
    float gg = pre[(size_t)(2 * H_ + j) * pre_ld + r] + bias[2 * H_ + j] + a2;
    float go = pre[(size_t)(3 * H_ + j) * pre_ld + r] + bias[3 * H_ + j] + a3;
    float co = cSt[j * 64 + lane];
    float si = 1.f / (1.f + expf(-gi));
    float sf = 1.f / (1.f + expf(-gf));
    float so = 1.f / (1.f + expf(-go));
    float cn = sf * co + si * tanhf(gg);
    float hn = so * tanhf(cn);
    cSt[j * 64 + lane] = cn;
    hOut[j * 64 + lane] = hn;
    outD[(size_t)j * out_ld + col + lane] = hn;
}

// ---------------- emission accumulate for one chunk of one direction
// h1C [600][cols]; ys[b][t0+tl][l] += sum_k h1C[k][tl*64+b] * Wc[k*4+l] (+bc if addBias)
__global__ __launch_bounds__(256) void emis_add(const float* __restrict__ h1C, int cols,
                                                const float* __restrict__ Wc,
                                                const float* __restrict__ bc, int addBias,
                                                float* __restrict__ ys, int t0) {
    int lane = threadIdx.x & 63;
    int l = __builtin_amdgcn_readfirstlane(threadIdx.x >> 6);
    int tl = blockIdx.x;
    float acc = addBias ? bc[l] : 0.f;
    for (int k = 0; k < H_; ++k)
        acc = fmaf(h1C[(size_t)k * cols + tl * 64 + lane], Wc[k * 4 + l], acc);
    int t = t0 + tl, b = lane;
    ys[((size_t)b * T_ + t) * 4 + l] += acc;
}

// ---------------- CRF log-likelihood per batch
__global__ void crf_fwd(const float* __restrict__ ys, const int* __restrict__ ls,
                        const float* __restrict__ trans, const float* __restrict__ startT,
                        const float* __restrict__ endT, float* __restrict__ llb) {
    int b = blockIdx.x;
    int lane = threadIdx.x;
    float acc = 0.f;
    for (int t = lane; t < T_; t += 64) {
        int tg = ls[b * T_ + t];
        acc += ys[((size_t)b * T_ + t) * 4 + tg];
        if (t > 0) acc += trans[ls[b * T_ + t - 1] * 4 + tg];
    }
    for (int off = 32; off; off >>= 1) acc += __shfl_down(acc, off);
    float num = 0.f;
    if (lane == 0) num = startT[ls[b * T_]] + acc + endT[ls[b * T_ + T_ - 1]];

    float a = -1e30f;
    if (lane < 4) a = startT[lane] + ys[((size_t)b * T_) * 4 + lane];
    for (int t = 1; t < T_; ++t) {
        float a0 = __shfl(a, 0), a1 = __shfl(a, 1), a2 = __shfl(a, 2), a3 = __shfl(a, 3);
        if (lane < 4) {
            float v0 = a0 + trans[0 * 4 + lane];
            float v1 = a1 + trans[1 * 4 + lane];
            float v2 = a2 + trans[2 * 4 + lane];
            float v3 = a3 + trans[3 * 4 + lane];
            float mx = fmaxf(fmaxf(v0, v1), fmaxf(v2, v3));
            float ssum = expf(v0 - mx) + expf(v1 - mx) + expf(v2 - mx) + expf(v3 - mx);
            a = mx + logf(ssum) + ys[((size_t)b * T_ + t) * 4 + lane];
        }
    }
    float a0 = __shfl(a, 0), a1 = __shfl(a, 1), a2 = __shfl(a, 2), a3 = __shfl(a, 3);
    if (lane == 0) {
        float v0 = a0 + endT[0], v1 = a1 + endT[1], v2 = a2 + endT[2], v3 = a3 + endT[3];
        float mx = fmaxf(fmaxf(v0, v1), fmaxf(v2, v3));
        float den = mx + logf(expf(v0 - mx) + expf(v1 - mx) + expf(v2 - mx) + expf(v3 - mx));
        llb[b] = num - den;
    }
}

__global__ void final_loss(const float* __restrict__ llb, float* __restrict__ out) {
    int lane = threadIdx.x;
    float v = llb[lane];
    for (int off = 32; off; off >>= 1) v += __shfl_down(v, off);
    if (lane == 0) out[0] = -v / 64.0f;
}

// ---------------- Viterbi decode (tags written as float at out[1..])
__global__ void viterbi(const float* __restrict__ ys, const float* __restrict__ trans,
                        const float* __restrict__ startT, const float* __restrict__ endT,
                        float* __restrict__ out) {
    __shared__ unsigned char bp[T_ * 4];
    int b = blockIdx.x;
    int lane = threadIdx.x;
    float a = -1e30f;
    if (lane < 4) a = startT[lane] + ys[((size_t)b * T_) * 4 + lane];
    for (int t = 1; t < T_; ++t) {
        float a0 = __shfl(a, 0), a1 = __shfl(a, 1), a2 = __shfl(a, 2), a3 = __shfl(a, 3);
        if (lane < 4) {
            float av[4] = {a0, a1, a2, a3};
            float best = av[0] + trans[lane];
            int bi = 0;
            for (int lp = 1; lp < 4; ++lp) {
                float v = av[lp] + trans[lp * 4 + lane];
                if (v > best) { best = v; bi = lp; }
            }
            bp[t * 4 + lane] = (unsigned char)bi;
            a = best + ys[((size_t)b * T_ + t) * 4 + lane];
        }
    }
    float a0 = __shfl(a, 0), a1 = __shfl(a, 1), a2 = __shfl(a, 2), a3 = __shfl(a, 3);
    if (lane == 0) {
        float v[4] = {a0 + endT[0], a1 + endT[1], a2 + endT[2], a3 + endT[3]};
        int tag = 0;
        float best = v[0];
        for (int l = 1; l < 4; ++l)
            if (v[l] > best) { best = v[l]; tag = l; }
        out[1 + b * T_ + (T_ - 1)] = (float)tag;
        for (int t = T_ - 1; t >= 1; --t) {
            tag = bp[t * 4 + tag];
            out[1 + b * T_ + t - 1] = (float)tag;
        }
    }
}

extern "C" void kernel_launch(void* const* d_in, const int* in_sizes, int n_in,
                              void* d_out, int out_size, void* d_ws, size_t ws_size,
                              hipStream_t stream) {
    const int* us = (const int*)d_in[0];
    const int* ls = (const int*)d_in[1];
    const float* embed = (const float*)d_in[2];
    const float* Wih0f = (const float*)d_in[3];
    const float* Whh0f = (const float*)d_in[4];
    const float* b0f   = (const float*)d_in[5];
    const float* Wih0b = (const float*)d_in[6];
    const float* Whh0b = (const float*)d_in[7];
    const float* b0b   = (const float*)d_in[8];
    const float* Wih1f = (const float*)d_in[9];
    const float* Whh1f = (const float*)d_in[10];
    const float* b1f   = (const float*)d_in[11];
    const float* Wih1b = (const float*)d_in[12];
    const float* Whh1b = (const float*)d_in[13];
    const float* b1b   = (const float*)d_in[14];
    const float* W1    = (const float*)d_in[15];
    const float* bm1   = (const float*)d_in[16];
    const float* W2    = (const float*)d_in[17];
    const float* bm2   = (const float*)d_in[18];
    const float* trans = (const float*)d_in[19];
    const float* startT= (const float*)d_in[20];
    const float* endT  = (const float*)d_in[21];
    float* out = (float*)d_out;

    char* p = (char*)d_ws;
    auto alloc = [&](size_t bytes) {
        char* r = p;
        p += (bytes + 255) & ~(size_t)255;
        return r;
    };
    float* xT  = (float*)alloc((size_t)E_ * MTOT * 4);        // 33.5 MB
    float* h0T = (float*)alloc((size_t)1200 * MTOT * 4);      // 157 MB
    float* states = (float*)alloc((size_t)6 * H_ * 64 * 4);   // 0.9 MB
    float* Wc  = (float*)alloc(4800 * 4);
    float* bc  = (float*)alloc(4 * 4);
    float* ysb = (float*)alloc((size_t)B_ * T_ * 4 * 4);      // 2 MB
    float* llb = (float*)alloc(64 * 4);

    size_t used = (size_t)(p - (char*)d_ws);
    // per-Tc-unit bytes: preF+preB (2*G4*64*4) + h1fC+h1bC (2*H_*64*4)
    size_t perTc = (size_t)2 * G4 * 64 * 4 + (size_t)2 * H_ * 64 * 4;
    int Tc = 128;
    while (Tc > 8 && used + (size_t)Tc * perTc + 4096 > ws_size) Tc >>= 1;
    float* preF = (float*)alloc((size_t)G4 * Tc * 64 * 4);
    float* preB = (float*)alloc((size_t)G4 * Tc * 64 * 4);
    float* h1fC = (float*)alloc((size_t)H_ * Tc * 64 * 4);
    float* h1bC = (float*)alloc((size_t)H_ * Tc * 64 * 4);
    int nc = T_ / Tc;
    int chunkRows = Tc * 64;

    gather_xT<<<MTOT / 64, 256, 0, stream>>>(us, embed, xT);
    wc_kernel<<<19, 256, 0, stream>>>(W1, bm1, W2, bm2, Wc, bc);
    zero_kernel<<<(B_ * T_ * 4 + 255) / 256, 256, 0, stream>>>(ysb, B_ * T_ * 4);

    float* hA_f = states + 0 * 38400;
    float* hB_f = states + 1 * 38400;
    float* c_f  = states + 2 * 38400;
    float* hA_b = states + 3 * 38400;
    float* hB_b = states + 4 * 38400;
    float* c_b  = states + 5 * 38400;

    for (int layer = 0; layer < 2; ++layer) {
        const float* AT = layer ? h0T : xT;
        int K = layer ? 1200 : 256;
        const float* WiF = layer ? Wih1f : Wih0f;
        const float* WiB = layer ? Wih1b : Wih0b;
        const float* WhF = layer ? Whh1f : Whh0f;
        const float* WhB = layer ? Whh1b : Whh0b;
        const float* bF  = layer ? b1f : b0f;
        const float* bB  = layer ? b1b : b0b;

        zero_kernel<<<(6 * H_ * 64 + 255) / 256, 256, 0, stream>>>(states, 6 * H_ * 64);

        for (int c = 0; c < nc; ++c) {
            int moffF = c * Tc * 64;
            int moffB = (T_ - (c + 1) * Tc) * 64;
            dim3 gg(19, chunkRows / GBM);
            gemm_nt<<<gg, 256, 0, stream>>>(AT, MTOT, moffF, WiF, G4, K, preF, chunkRows);
            gemm_nt<<<gg, 256, 0, stream>>>(AT, MTOT, moffB, WiB, G4, K, preB, chunkRows);
            for (int s = 0; s < Tc; ++s) {
                int step = c * Tc + s;
                int par = step & 1;
                float* outF; int colF; float* outB; int colB; int oldd;
                if (layer == 0) {
                    outF = h0T;               colF = step * 64;
                    outB = h0T + (size_t)600 * MTOT; colB = (T_ - 1 - step) * 64;
                    oldd = MTOT;
                } else {
                    outF = h1fC;              colF = s * 64;
                    outB = h1bC;              colB = (Tc - 1 - s) * 64;
                    oldd = chunkRows;
                }
                lstm_step<<<300, 256, 0, stream>>>(
                    preF, preB, chunkRows, s, Tc - 1 - s,
                    WhF, WhB, bF, bB,
                    par ? hB_f : hA_f, par ? hA_f : hB_f, c_f,
                    par ? hB_b : hA_b, par ? hA_b : hB_b, c_b,
                    outF, colF, outB, colB, oldd);
            }
            if (layer == 1) {
                emis_add<<<Tc, 256, 0, stream>>>(h1fC, chunkRows, Wc, bc, 1, ysb, c * Tc);
                emis_add<<<Tc, 256, 0, stream>>>(h1bC, chunkRows, Wc + 600 * 4, bc, 0, ysb,
                                                 T_ - (c + 1) * Tc);
            }
        }
    }

    crf_fwd<<<B_, 64, 0, stream>>>(ysb, ls, trans, startT, endT, llb);
    final_loss<<<1, 64, 0, stream>>>(llb, out);
    viterbi<<<B_, 64, 0, stream>>>(ysb, trans, startT, endT, out);
}

// Round 3
// 35678.226 us; speedup vs baseline: 1.0324x; 1.0324x over previous
//
#include <hip/hip_runtime.h>
#include <hip/hip_bf16.h>
#include <math.h>

#define T_ 512
#define B_ 64
#define E_ 256
#define H_ 600
#define G4 2400    // 4*H
#define MTOT 32768 // T*B
#define LDW 2432   // padded WT width (2400 -> 19*128)

// ---------------- generic zero
__global__ __launch_bounds__(256) void zero_kernel(float* __restrict__ p, int n) {
    int i = blockIdx.x * 256 + threadIdx.x;
    if (i < n) p[i] = 0.f;
}

// ---------------- embedding gather: xT[k][m] = embed[us[b,t]*E + k], m = t*64+b
__global__ __launch_bounds__(256) void gather_xT(const int* __restrict__ us,
                                                 const float* __restrict__ embed,
                                                 float* __restrict__ xT) {
    int lane = threadIdx.x & 63;
    int m = blockIdx.x * 64 + lane;
    int b = m & 63, t = m >> 6;
    int tok = us[b * T_ + t];
    for (int k = threadIdx.x >> 6; k < E_; k += 4)
        xT[(size_t)k * MTOT + m] = embed[(size_t)tok * E_ + k];
}

// ---------------- Wc = W1 @ W2  [1200,4], bc = bm1 @ W2 + bm2  [4]
__global__ void wc_kernel(const float* __restrict__ W1, const float* __restrict__ bm1,
                          const float* __restrict__ W2, const float* __restrict__ bm2,
                          float* __restrict__ Wc, float* __restrict__ bc) {
    int idx = blockIdx.x * 256 + threadIdx.x;
    if (idx < 4800) {
        int k = idx >> 2, l = idx & 3;
        float acc = 0.f;
        for (int j = 0; j < 600; ++j) acc += W1[(size_t)k * 600 + j] * W2[j * 4 + l];
        Wc[idx] = acc;
    }
    if (idx < 4) {
        float acc = bm2[idx];
        for (int j = 0; j < 600; ++j) acc += bm1[j] * W2[j * 4 + idx];
        bc[idx] = acc;
    }
}

// ---------------- W [2400][K] -> WT [K][LDW], cols >= 2400 zeroed
__global__ __launch_bounds__(256) void transpose_w(const float* __restrict__ Wf,
                                                   const float* __restrict__ Wb, int K,
                                                   float* __restrict__ WTf,
                                                   float* __restrict__ WTb) {
    __shared__ float t[32][33];
    const float* W = blockIdx.z ? Wb : Wf;
    float* WT = blockIdx.z ? WTb : WTf;
    int n0 = blockIdx.x * 32, k0 = blockIdx.y * 32;
    int j = threadIdx.x & 31, i0 = threadIdx.x >> 5;
#pragma unroll
    for (int r = 0; r < 4; ++r) {
        int i = i0 + r * 8;
        int n = n0 + i, k = k0 + j;
        t[i][j] = (n < G4 && k < K) ? W[(size_t)n * K + k] : 0.f;
    }
    __syncthreads();
#pragma unroll
    for (int r = 0; r < 4; ++r) {
        int i = i0 + r * 8;
        int k = k0 + i;
        if (k < K) WT[(size_t)k * LDW + n0 + j] = t[j][i];
    }
}

// ---------------- fp32 GEMM: pre[n][m] = sum_k AT[k][m_off+m] * WT[k][n]
// grid (19, chunkRows/128, 2); z selects direction
#define GBM 128
#define GBN 128
#define GBK 32
__global__ __launch_bounds__(256) void gemm_tn(const float* __restrict__ AT, int lda,
                                               int m_offF, int m_offB,
                                               const float* __restrict__ WTf,
                                               const float* __restrict__ WTb, int K,
                                               float* __restrict__ preF,
                                               float* __restrict__ preB, int ldc) {
    __shared__ float As[GBK][GBM + 4];
    __shared__ float Ws[GBK][GBN + 4];
    const float* WT = blockIdx.z ? WTb : WTf;
    float* CT = blockIdx.z ? preB : preF;
    int m_off = blockIdx.z ? m_offB : m_offF;
    int tid = threadIdx.x;
    int n0 = blockIdx.x * GBN, m0 = blockIdx.y * GBM;
    int tx = tid & 15, ty = tid >> 4;
    int skk = tid >> 3, scol = (tid & 7) * 16;

    float4 ra[4], rw[4];
    const float4 z4 = make_float4(0.f, 0.f, 0.f, 0.f);
    {
        bool inK = skk < K;
        const float4* aSrc = (const float4*)(AT + (size_t)skk * lda + m_off + m0 + scol);
        const float4* wSrc = (const float4*)(WT + (size_t)skk * LDW + n0 + scol);
#pragma unroll
        for (int r = 0; r < 4; ++r) {
            ra[r] = inK ? aSrc[r] : z4;
            rw[r] = inK ? wSrc[r] : z4;
        }
    }

    float acc[8][8] = {};
    for (int k0 = 0; k0 < K; k0 += GBK) {
        __syncthreads();
        *(float4*)&As[skk][scol]      = ra[0];
        *(float4*)&As[skk][scol + 4]  = ra[1];
        *(float4*)&As[skk][scol + 8]  = ra[2];
        *(float4*)&As[skk][scol + 12] = ra[3];
        *(float4*)&Ws[skk][scol]      = rw[0];
        *(float4*)&Ws[skk][scol + 4]  = rw[1];
        *(float4*)&Ws[skk][scol + 8]  = rw[2];
        *(float4*)&Ws[skk][scol + 12] = rw[3];
        __syncthreads();
        int kn = k0 + GBK;
        if (kn < K) {
            bool inK = (kn + skk) < K;
            const float4* aSrc = (const float4*)(AT + (size_t)(kn + skk) * lda + m_off + m0 + scol);
            const float4* wSrc = (const float4*)(WT + (size_t)(kn + skk) * LDW + n0 + scol);
#pragma unroll
            for (int r = 0; r < 4; ++r) {
                ra[r] = inK ? aSrc[r] : z4;
                rw[r] = inK ? wSrc[r] : z4;
            }
        }
#pragma unroll
        for (int kk = 0; kk < GBK; ++kk) {
            float a[8], w[8];
            *(float4*)&a[0] = *(float4*)&As[kk][tx * 8];
            *(float4*)&a[4] = *(float4*)&As[kk][tx * 8 + 4];
            *(float4*)&w[0] = *(float4*)&Ws[kk][ty * 8];
            *(float4*)&w[4] = *(float4*)&Ws[kk][ty * 8 + 4];
#pragma unroll
            for (int j = 0; j < 8; ++j)
#pragma unroll
                for (int i = 0; i < 8; ++i)
                    acc[j][i] = fmaf(w[j], a[i], acc[j][i]);
        }
    }
#pragma unroll
    for (int j = 0; j < 8; ++j) {
        int n = n0 + ty * 8 + j;
        if (n < G4) {
            float* dst = CT + (size_t)n * ldc + m0 + tx * 8;
            *(float4*)dst = *(float4*)&acc[j][0];
            *(float4*)(dst + 4) = *(float4*)&acc[j][4];
        }
    }
}

// ---------------- one LSTM time step, both directions.
// grid: 300 blocks (150/dir, 4 hidden units per block, 1 per wave), 256 threads
__global__ __launch_bounds__(256) void lstm_step(
    const float* __restrict__ preF, const float* __restrict__ preB, int pre_ld,
    int sF, int sB,
    const float* __restrict__ WhhF, const float* __restrict__ WhhB,
    const float* __restrict__ biasF, const float* __restrict__ biasB,
    const float* __restrict__ hInF, float* __restrict__ hOutF, float* __restrict__ cF,
    const float* __restrict__ hInB, float* __restrict__ hOutB, float* __restrict__ cB,
    float* __restrict__ outF, int colF, float* __restrict__ outB, int colB, int out_ld) {
    __shared__ float lh[120 * 64];
    int tid = threadIdx.x;
    int lane = tid & 63;
    int dir = (blockIdx.x >= 150) ? 1 : 0;
    int jb = blockIdx.x - dir * 150;
    int j = __builtin_amdgcn_readfirstlane(jb * 4 + (tid >> 6));
    const float* pre = dir ? preB : preF;
    const float* Whh = dir ? WhhB : WhhF;
    const float* bias = dir ? biasB : biasF;
    const float* hIn = dir ? hInB : hInF;
    float* hOut = dir ? hOutB : hOutF;
    float* cSt = dir ? cB : cF;
    float* outD = dir ? outB : outF;
    int s = dir ? sB : sF;
    int col = dir ? colB : colF;

    const float4* w0v = (const float4*)(Whh + (size_t)(0 * H_ + j) * H_);
    const float4* w1v = (const float4*)(Whh + (size_t)(1 * H_ + j) * H_);
    const float4* w2v = (const float4*)(Whh + (size_t)(2 * H_ + j) * H_);
    const float4* w3v = (const float4*)(Whh + (size_t)(3 * H_ + j) * H_);

    float a0 = 0.f, a1 = 0.f, a2 = 0.f, a3 = 0.f;
    for (int k0 = 0; k0 < H_; k0 += 120) {
        __syncthreads();
        {
            const float4* src = (const float4*)(hIn + (size_t)k0 * 64);
            float4* dst = (float4*)lh;
            for (int u = tid; u < 1920; u += 256) dst[u] = src[u];
        }
        __syncthreads();
        int q0 = k0 >> 2;
#pragma unroll
        for (int q = 0; q < 30; ++q) {
            float4 wa = w0v[q0 + q], wb = w1v[q0 + q], wc = w2v[q0 + q], wd = w3v[q0 + q];
            const float* pa = (const float*)&wa;
            const float* pb = (const float*)&wb;
            const float* pc = (const float*)&wc;
            const float* pd = (const float*)&wd;
#pragma unroll
            for (int e = 0; e < 4; ++e) {
                float hv = lh[(q * 4 + e) * 64 + lane];
                a0 = fmaf(hv, pa[e], a0);
                a1 = fmaf(hv, pb[e], a1);
                a2 = fmaf(hv, pc[e], a2);
                a3 = fmaf(hv, pd[e], a3);
            }
        }
    }
    int r = s * 64 + lane;
    float gi = pre[(size_t)(0 * H_ + j) * pre_ld + r] + bias[0 * H_ + j] + a0;
    float gf = pre[(size_t)(1 * H_ + j) * pre_ld + r] + bias[1 * H_ + j] + a1;
    float gg = pre[(size_t)(2 * H_ + j) * pre_ld + r] + bias[2 * H_ + j] + a2;
    float go = pre[(size_t)(3 * H_ + j) * pre_ld + r] + bias[3 * H_ + j] + a3;
    float co = cSt[j * 64 + lane];
    float si = 1.f / (1.f + expf(-gi));
    float sf = 1.f / (1.f + expf(-gf));
    float so = 1.f / (1.f + expf(-go));
    float cn = sf * co + si * tanhf(gg);
    float hn = so * tanhf(cn);
    cSt[j * 64 + lane] = cn;
    hOut[j * 64 + lane] = hn;
    outD[(size_t)j * out_ld + col + lane] = hn;
}

// ---------------- emission accumulate for one chunk of one direction
__global__ __launch_bounds__(256) void emis_add(const float* __restrict__ h1C, int cols,
                                                const float* __restrict__ Wc,
                                                const float* __restrict__ bc, int addBias,
                                                float* __restrict__ ys, int t0) {
    int lane = threadIdx.x & 63;
    int l = __builtin_amdgcn_readfirstlane(threadIdx.x >> 6);
    int tl = blockIdx.x;
    float acc = addBias ? bc[l] : 0.f;
    for (int k = 0; k < H_; ++k)
        acc = fmaf(h1C[(size_t)k * cols + tl * 64 + lane], Wc[k * 4 + l], acc);
    int t = t0 + tl, b = lane;
    ys[((size_t)b * T_ + t) * 4 + l] += acc;
}

// ---------------- CRF log-likelihood per batch
__global__ void crf_fwd(const float* __restrict__ ys, const int* __restrict__ ls,
                        const float* __restrict__ trans, const float* __restrict__ startT,
                        const float* __restrict__ endT, float* __restrict__ llb) {
    int b = blockIdx.x;
    int lane = threadIdx.x;
    float acc = 0.f;
    for (int t = lane; t < T_; t += 64) {
        int tg = ls[b * T_ + t];
        acc += ys[((size_t)b * T_ + t) * 4 + tg];
        if (t > 0) acc += trans[ls[b * T_ + t - 1] * 4 + tg];
    }
    for (int off = 32; off; off >>= 1) acc += __shfl_down(acc, off);
    float num = 0.f;
    if (lane == 0) num = startT[ls[b * T_]] + acc + endT[ls[b * T_ + T_ - 1]];

    float a = -1e30f;
    if (lane < 4) a = startT[lane] + ys[((size_t)b * T_) * 4 + lane];
    for (int t = 1; t < T_; ++t) {
        float a0 = __shfl(a, 0), a1 = __shfl(a, 1), a2 = __shfl(a, 2), a3 = __shfl(a, 3);
        if (lane < 4) {
            float v0 = a0 + trans[0 * 4 + lane];
            float v1 = a1 + trans[1 * 4 + lane];
            float v2 = a2 + trans[2 * 4 + lane];
            float v3 = a3 + trans[3 * 4 + lane];
            float mx = fmaxf(fmaxf(v0, v1), fmaxf(v2, v3));
            float ssum = expf(v0 - mx) + expf(v1 - mx) + expf(v2 - mx) + expf(v3 - mx);
            a = mx + logf(ssum) + ys[((size_t)b * T_ + t) * 4 + lane];
        }
    }
    float a0 = __shfl(a, 0), a1 = __shfl(a, 1), a2 = __shfl(a, 2), a3 = __shfl(a, 3);
    if (lane == 0) {
        float v0 = a0 + endT[0], v1 = a1 + endT[1], v2 = a2 + endT[2], v3 = a3 + endT[3];
        float mx = fmaxf(fmaxf(v0, v1), fmaxf(v2, v3));
        float den = mx + logf(expf(v0 - mx) + expf(v1 - mx) + expf(v2 - mx) + expf(v3 - mx));
        llb[b] = num - den;
    }
}

__global__ void final_loss(const float* __restrict__ llb, float* __restrict__ out) {
    int lane = threadIdx.x;
    float v = llb[lane];
    for (int off = 32; off; off >>= 1) v += __shfl_down(v, off);
    if (lane == 0) out[0] = -v / 64.0f;
}

// ---------------- Viterbi decode (tags written as float at out[1..])
__global__ void viterbi(const float* __restrict__ ys, const float* __restrict__ trans,
                        const float* __restrict__ startT, const float* __restrict__ endT,
                        float* __restrict__ out) {
    __shared__ unsigned char bp[T_ * 4];
    int b = blockIdx.x;
    int lane = threadIdx.x;
    float a = -1e30f;
    if (lane < 4) a = startT[lane] + ys[((size_t)b * T_) * 4 + lane];
    for (int t = 1; t < T_; ++t) {
        float a0 = __shfl(a, 0), a1 = __shfl(a, 1), a2 = __shfl(a, 2), a3 = __shfl(a, 3);
        if (lane < 4) {
            float av[4] = {a0, a1, a2, a3};
            float best = av[0] + trans[lane];
            int bi = 0;
            for (int lp = 1; lp < 4; ++lp) {
                float v = av[lp] + trans[lp * 4 + lane];
                if (v > best) { best = v; bi = lp; }
            }
            bp[t * 4 + lane] = (unsigned char)bi;
            a = best + ys[((size_t)b * T_ + t) * 4 + lane];
        }
    }
    float a0 = __shfl(a, 0), a1 = __shfl(a, 1), a2 = __shfl(a, 2), a3 = __shfl(a, 3);
    if (lane == 0) {
        float v[4] = {a0 + endT[0], a1 + endT[1], a2 + endT[2], a3 + endT[3]};
        int tag = 0;
        float best = v[0];
        for (int l = 1; l < 4; ++l)
            if (v[l] > best) { best = v[l]; tag = l; }
        out[1 + b * T_ + (T_ - 1)] = (float)tag;
        for (int t = T_ - 1; t >= 1; --t) {
            tag = bp[t * 4 + tag];
            out[1 + b * T_ + t - 1] = (float)tag;
        }
    }
}

extern "C" void kernel_launch(void* const* d_in, const int* in_sizes, int n_in,
                              void* d_out, int out_size, void* d_ws, size_t ws_size,
                              hipStream_t stream) {
    const int* us = (const int*)d_in[0];
    const int* ls = (const int*)d_in[1];
    const float* embed = (const float*)d_in[2];
    const float* Wih0f = (const float*)d_in[3];
    const float* Whh0f = (const float*)d_in[4];
    const float* b0f   = (const float*)d_in[5];
    const float* Wih0b = (const float*)d_in[6];
    const float* Whh0b = (const float*)d_in[7];
    const float* b0b   = (const float*)d_in[8];
    const float* Wih1f = (const float*)d_in[9];
    const float* Whh1f = (const float*)d_in[10];
    const float* b1f   = (const float*)d_in[11];
    const float* Wih1b = (const float*)d_in[12];
    const float* Whh1b = (const float*)d_in[13];
    const float* b1b   = (const float*)d_in[14];
    const float* W1    = (const float*)d_in[15];
    const float* bm1   = (const float*)d_in[16];
    const float* W2    = (const float*)d_in[17];
    const float* bm2   = (const float*)d_in[18];
    const float* trans = (const float*)d_in[19];
    const float* startT= (const float*)d_in[20];
    const float* endT  = (const float*)d_in[21];
    float* out = (float*)d_out;

    char* p = (char*)d_ws;
    auto alloc = [&](size_t bytes) {
        char* r = p;
        p += (bytes + 255) & ~(size_t)255;
        return r;
    };
    float* xT  = (float*)alloc((size_t)E_ * MTOT * 4);        // 33.5 MB
    float* h0T = (float*)alloc((size_t)1200 * MTOT * 4);      // 157 MB
    float* states = (float*)alloc((size_t)6 * H_ * 64 * 4);   // 0.9 MB
    float* Wc  = (float*)alloc(4800 * 4);
    float* bc  = (float*)alloc(4 * 4);
    float* ysb = (float*)alloc((size_t)B_ * T_ * 4 * 4);      // 2 MB
    float* llb = (float*)alloc(64 * 4);
    float* WT0f = (float*)alloc((size_t)E_ * LDW * 4);        // 2.5 MB
    float* WT0b = (float*)alloc((size_t)E_ * LDW * 4);
    float* WT1f = (float*)alloc((size_t)1200 * LDW * 4);      // 11.7 MB
    float* WT1b = (float*)alloc((size_t)1200 * LDW * 4);

    size_t used = (size_t)(p - (char*)d_ws);
    size_t perTc = (size_t)2 * G4 * 64 * 4 + (size_t)2 * H_ * 64 * 4;
    int Tc = 128;
    while (Tc > 8 && used + (size_t)Tc * perTc + 4096 > ws_size) Tc >>= 1;
    float* preF = (float*)alloc((size_t)G4 * Tc * 64 * 4);
    float* preB = (float*)alloc((size_t)G4 * Tc * 64 * 4);
    float* h1fC = (float*)alloc((size_t)H_ * Tc * 64 * 4);
    float* h1bC = (float*)alloc((size_t)H_ * Tc * 64 * 4);
    int nc = T_ / Tc;
    int chunkRows = Tc * 64;

    gather_xT<<<MTOT / 64, 256, 0, stream>>>(us, embed, xT);
    wc_kernel<<<19, 256, 0, stream>>>(W1, bm1, W2, bm2, Wc, bc);
    zero_kernel<<<(B_ * T_ * 4 + 255) / 256, 256, 0, stream>>>(ysb, B_ * T_ * 4);
    transpose_w<<<dim3(LDW / 32, E_ / 32, 2), 256, 0, stream>>>(Wih0f, Wih0b, E_, WT0f, WT0b);
    transpose_w<<<dim3(LDW / 32, (1200 + 31) / 32, 2), 256, 0, stream>>>(Wih1f, Wih1b, 1200, WT1f, WT1b);

    float* hA_f = states + 0 * 38400;
    float* hB_f = states + 1 * 38400;
    float* c_f  = states + 2 * 38400;
    float* hA_b = states + 3 * 38400;
    float* hB_b = states + 4 * 38400;
    float* c_b  = states + 5 * 38400;

    for (int layer = 0; layer < 2; ++layer) {
        const float* AT = layer ? h0T : xT;
        int K = layer ? 1200 : 256;
        const float* WTf = layer ? WT1f : WT0f;
        const float* WTb = layer ? WT1b : WT0b;
        const float* WhF = layer ? Whh1f : Whh0f;
        const float* WhB = layer ? Whh1b : Whh0b;
        const float* bF  = layer ? b1f : b0f;
        const float* bB  = layer ? b1b : b0b;

        zero_kernel<<<(6 * H_ * 64 + 255) / 256, 256, 0, stream>>>(states, 6 * H_ * 64);

        for (int c = 0; c < nc; ++c) {
            int moffF = c * Tc * 64;
            int moffB = (T_ - (c + 1) * Tc) * 64;
            dim3 gg(19, chunkRows / GBM, 2);
            gemm_tn<<<gg, 256, 0, stream>>>(AT, MTOT, moffF, moffB, WTf, WTb, K,
                                            preF, preB, chunkRows);
            for (int s = 0; s < Tc; ++s) {
                int step = c * Tc + s;
                int par = step & 1;
                float* outF; int colF; float* outB; int colB; int oldd;
                if (layer == 0) {
                    outF = h0T;               colF = step * 64;
                    outB = h0T + (size_t)600 * MTOT; colB = (T_ - 1 - step) * 64;
                    oldd = MTOT;
                } else {
                    outF = h1fC;              colF = s * 64;
                    outB = h1bC;              colB = (Tc - 1 - s) * 64;
                    oldd = chunkRows;
                }
                lstm_step<<<300, 256, 0, stream>>>(
                    preF, preB, chunkRows, s, Tc - 1 - s,
                    WhF, WhB, bF, bB,
                    par ? hB_f : hA_f, par ? hA_f : hB_f, c_f,
                    par ? hB_b : hA_b, par ? hA_b : hB_b, c_b,
                    outF, colF, outB, colB, oldd);
            }
            if (layer == 1) {
                emis_add<<<Tc, 256, 0, stream>>>(h1fC, chunkRows, Wc, bc, 1, ysb, c * Tc);
                emis_add<<<Tc, 256, 0, stream>>>(h1bC, chunkRows, Wc + 600 * 4, bc, 0, ysb,
                                                 T_ - (c + 1) * Tc);
            }
        }
    }

    crf_fwd<<<B_, 64, 0, stream>>>(ysb, ls, trans, startT, endT, llb);
    final_loss<<<1, 64, 0, stream>>>(llb, out);
    viterbi<<<B_, 64, 0, stream>>>(ysb, trans, startT, endT, out);
}